// Round 18
// baseline (148.027 us; speedup 1.0000x reference)
//
#include <hip/hip_runtime.h>
#include <hip/hip_bf16.h>

#define CAPU 64
#define CAPI 64

typedef __attribute__((ext_vector_type(8))) short bf16x8;
typedef __attribute__((ext_vector_type(4))) float f32x4;

static __device__ __forceinline__ float bflo(unsigned int w) {
    union { unsigned int i; float f; } u; u.i = w << 16; return u.f;
}
static __device__ __forceinline__ float bfhi(unsigned int w) {
    union { unsigned int i; float f; } u; u.i = w & 0xffff0000u; return u.f;
}
static __device__ __forceinline__ unsigned short f2bf(float f) {
    __hip_bfloat16 h = __float2bfloat16(f);
    union { __hip_bfloat16 b; unsigned short s; } u; u.b = h; return u.s;
}

// ---------------------------------------------------------------------------
// split scatter: nt loads for src/dst (streaming), nt stores for buckets
// (single-use until convs) -> keep L2 for atomics counters + tables.
// ---------------------------------------------------------------------------
__global__ void scatter_kernel(const int* __restrict__ src, const int* __restrict__ dst,
                               int* __restrict__ wpu, int* __restrict__ wpi,
                               int* __restrict__ uedges, int* __restrict__ iedges,
                               int nu, int E) {
    int e = blockIdx.x * blockDim.x + threadIdx.x;
    if (e < E) {
        int d = __builtin_nontemporal_load(&dst[e]);
        int s = __builtin_nontemporal_load(&src[e]);
        if (s < nu) {
            int p = atomicAdd(&wpu[d], 1);
            if (p < CAPU) __builtin_nontemporal_store(s, &uedges[d * CAPU + p]);
        } else {
            int p = atomicAdd(&wpi[d], 1);
            if (p < CAPI) __builtin_nontemporal_store(s - nu, &iedges[d * CAPI + p]);
        }
    }
}

__global__ void dinv_kernel(const int* __restrict__ wpu, const int* __restrict__ wpi,
                            float* __restrict__ dinv, int n) {
    int v = blockIdx.x * blockDim.x + threadIdx.x;
    if (v < n) dinv[v] = rsqrtf((float)(wpu[v] + wpi[v] + 1));
}

// ---------------------------------------------------------------------------
// merged prep (unchanged)
// ---------------------------------------------------------------------------
__global__ void prep_kernel(const int* __restrict__ x, const float* __restrict__ emb,
                            const float* __restrict__ W1, const float* __restrict__ W2,
                            const float* __restrict__ Wl,
                            unsigned short* __restrict__ hi,
                            unsigned short* __restrict__ h0u,
                            unsigned short* __restrict__ W1t,
                            unsigned short* __restrict__ W2t,
                            unsigned short* __restrict__ Wlt,
                            int* __restrict__ wpu, int* __restrict__ wpi,
                            int nu, int n) {
    int i = blockIdx.x * blockDim.x + threadIdx.x;
    int ni = n - nu;
    int HI = ni * 16;
    if (i < HI) {
        int it = i >> 4, c8 = i & 15;
        int row = x[nu + it] - nu + 1;
        float4 f0 = reinterpret_cast<const float4*>(emb)[(size_t)row * 32 + c8 * 2];
        float4 f1 = reinterpret_cast<const float4*>(emb)[(size_t)row * 32 + c8 * 2 + 1];
        union { unsigned short s[8]; uint4 v; } o;
        o.s[0] = f2bf(f0.x); o.s[1] = f2bf(f0.y); o.s[2] = f2bf(f0.z); o.s[3] = f2bf(f0.w);
        o.s[4] = f2bf(f1.x); o.s[5] = f2bf(f1.y); o.s[6] = f2bf(f1.z); o.s[7] = f2bf(f1.w);
        *reinterpret_cast<uint4*>(hi + (size_t)it * 128 + c8 * 8) = o.v;
        return;
    }
    int j = i - HI;
    if (j < 16) {
        int c8 = j;
        float4 f0 = reinterpret_cast<const float4*>(emb)[c8 * 2];
        float4 f1 = reinterpret_cast<const float4*>(emb)[c8 * 2 + 1];
        union { unsigned short s[8]; uint4 v; } o;
        o.s[0] = f2bf(f0.x); o.s[1] = f2bf(f0.y); o.s[2] = f2bf(f0.z); o.s[3] = f2bf(f0.w);
        o.s[4] = f2bf(f1.x); o.s[5] = f2bf(f1.y); o.s[6] = f2bf(f1.z); o.s[7] = f2bf(f1.w);
        *reinterpret_cast<uint4*>(h0u + c8 * 8) = o.v;
        return;
    }
    j -= 16;
    if (j < 32768) {
        int nn = j >> 7, kk = j & 127;
        W1t[j] = f2bf(W1[kk * 256 + nn]);
        return;
    }
    if (j < 65536) {
        int jj = j - 32768;
        int nn = jj >> 8, kk = jj & 255;
        W2t[jj] = f2bf(W2[kk * 128 + nn]);
        return;
    }
    if (j < 73728) {
        int jj = j - 65536;
        int nn = jj >> 7, kk = jj & 127;
        Wlt[jj] = f2bf(Wl[kk * 64 + nn]);
        return;
    }
    int z = j - 73728;
    if (z < n) { wpu[z] = 0; return; }
    z -= n;
    if (z < n) { wpi[z] = 0; }
}

// ---------------------------------------------------------------------------
// acc += w * unpack(row)
// ---------------------------------------------------------------------------
static __device__ __forceinline__ void row_fma(float w, uint4 r, float acc[8]) {
    acc[0] = fmaf(w, bflo(r.x), acc[0]); acc[1] = fmaf(w, bfhi(r.x), acc[1]);
    acc[2] = fmaf(w, bflo(r.y), acc[2]); acc[3] = fmaf(w, bfhi(r.y), acc[3]);
    acc[4] = fmaf(w, bflo(r.z), acc[4]); acc[5] = fmaf(w, bfhi(r.z), acc[5]);
    acc[6] = fmaf(w, bflo(r.w), acc[6]); acc[7] = fmaf(w, bfhi(r.w), acc[7]);
}

// ---------------------------------------------------------------------------
// subgroup-per-node gather; EDGE LIST loads are non-temporal (streaming,
// single-use) so they don't evict the gather table from L2.
// ---------------------------------------------------------------------------
static __device__ __forceinline__ void gather_sg(
    const unsigned short* __restrict__ in, int rofs,
    const int* __restrict__ lst, int base, int cnt,
    const float* __restrict__ dinv, int dofs, int l16, float acc[8]) {
    int e = base, end = base + cnt;
    for (; e + 3 < end; e += 4) {
        int sa = __builtin_nontemporal_load(&lst[e]);
        int sb = __builtin_nontemporal_load(&lst[e + 1]);
        int sc = __builtin_nontemporal_load(&lst[e + 2]);
        int sd = __builtin_nontemporal_load(&lst[e + 3]);
        float wa = dinv[sa + dofs], wb = dinv[sb + dofs];
        float wc = dinv[sc + dofs], wd = dinv[sd + dofs];
        uint4 ra = *reinterpret_cast<const uint4*>(in + (size_t)(sa + rofs) * 128 + l16 * 8);
        uint4 rb = *reinterpret_cast<const uint4*>(in + (size_t)(sb + rofs) * 128 + l16 * 8);
        uint4 rc = *reinterpret_cast<const uint4*>(in + (size_t)(sc + rofs) * 128 + l16 * 8);
        uint4 rd = *reinterpret_cast<const uint4*>(in + (size_t)(sd + rofs) * 128 + l16 * 8);
        row_fma(wa, ra, acc); row_fma(wb, rb, acc);
        row_fma(wc, rc, acc); row_fma(wd, rd, acc);
    }
    for (; e < end; ++e) {
        int sa = __builtin_nontemporal_load(&lst[e]);
        float wa = dinv[sa + dofs];
        uint4 ra = *reinterpret_cast<const uint4*>(in + (size_t)(sa + rofs) * 128 + l16 * 8);
        row_fma(wa, ra, acc);
    }
}

// ---------------------------------------------------------------------------
// fused conv1: block = 16 nodes, subgroup-per-node agg. -> gemm1 -> gemm2
// ---------------------------------------------------------------------------
__global__ __launch_bounds__(256, 4) void fused_conv1_kernel(
    const unsigned short* __restrict__ hi, const unsigned short* __restrict__ h0u,
    unsigned short* __restrict__ hw2b,
    const int* __restrict__ wpu, const int* __restrict__ wpi,
    const int* __restrict__ uedges, const int* __restrict__ iedges,
    const float* __restrict__ dinv,
    const unsigned short* __restrict__ W1t, const float* __restrict__ b1,
    const unsigned short* __restrict__ W2t, int nu) {
    __shared__ unsigned short zt[16][136];
    __shared__ unsigned short h1t[16][264];
    int wid = threadIdx.x >> 6, lane = threadIdx.x & 63;
    int l16 = lane & 15, g = lane >> 4;
    int base = blockIdx.x * 16;
    {
        int loc = wid * 4 + g;
        int v = base + loc;
        float su = 0.f;
        int cu = min(wpu[v], CAPU);
        for (int u = l16; u < cu; u += 16)
            su += dinv[__builtin_nontemporal_load(&uedges[v * CAPU + u])];
        su += __shfl_xor(su, 1, 64);
        su += __shfl_xor(su, 2, 64);
        su += __shfl_xor(su, 4, 64);
        su += __shfl_xor(su, 8, 64);
        float acc[8] = {0.f, 0.f, 0.f, 0.f, 0.f, 0.f, 0.f, 0.f};
        int ci = min(wpi[v], CAPI);
        gather_sg(hi, 0, iedges, v * CAPI, ci, dinv, nu, l16, acc);
        float dv = dinv[v];
        const unsigned short* selfp = (v < nu) ? h0u : (hi + (size_t)(v - nu) * 128);
        uint4 sp = *reinterpret_cast<const uint4*>(selfp + l16 * 8);
        uint4 hu = *reinterpret_cast<const uint4*>(h0u + l16 * 8);
        float selff[8] = {bflo(sp.x), bfhi(sp.x), bflo(sp.y), bfhi(sp.y),
                          bflo(sp.z), bfhi(sp.z), bflo(sp.w), bfhi(sp.w)};
        float huf[8] = {bflo(hu.x), bfhi(hu.x), bflo(hu.y), bfhi(hu.y),
                        bflo(hu.z), bfhi(hu.z), bflo(hu.w), bfhi(hu.w)};
        union { unsigned short s[8]; uint4 u; } o;
#pragma unroll
        for (int d = 0; d < 8; ++d) {
            float val = (acc[d] + su * huf[d] + dv * selff[d]) * dv;
            o.s[d] = f2bf(val);
        }
        *reinterpret_cast<uint4*>(&zt[loc][l16 * 8]) = o.u;
    }
    __syncthreads();
    int lr = lane & 15, kg = (lane >> 4) * 8;
    int rq = (lane >> 4) * 4;
    {
        int bn = wid * 64;
        f32x4 acc[4] = {{0,0,0,0},{0,0,0,0},{0,0,0,0},{0,0,0,0}};
        for (int k0 = 0; k0 < 128; k0 += 32) {
            bf16x8 a = *reinterpret_cast<const bf16x8*>(&zt[lr][k0 + kg]);
#pragma unroll
            for (int c = 0; c < 4; ++c) {
                bf16x8 b = *reinterpret_cast<const bf16x8*>(W1t + (size_t)(bn + c * 16 + lr) * 128 + k0 + kg);
                acc[c] = __builtin_amdgcn_mfma_f32_16x16x32_bf16(a, b, acc[c], 0, 0, 0);
            }
        }
#pragma unroll
        for (int c = 0; c < 4; ++c) {
            int col = bn + c * 16 + lr;
            float bs = b1[col];
#pragma unroll
            for (int q = 0; q < 4; ++q) {
                float vv = fmaxf(acc[c][q] + bs, 0.f);
                h1t[rq + q][col] = f2bf(vv);
            }
        }
    }
    __syncthreads();
    {
        int bn = wid * 32;
        f32x4 acc[2] = {{0,0,0,0},{0,0,0,0}};
        for (int k0 = 0; k0 < 256; k0 += 32) {
            bf16x8 a = *reinterpret_cast<const bf16x8*>(&h1t[lr][k0 + kg]);
#pragma unroll
            for (int c = 0; c < 2; ++c) {
                bf16x8 b = *reinterpret_cast<const bf16x8*>(W2t + (size_t)(bn + c * 16 + lr) * 256 + k0 + kg);
                acc[c] = __builtin_amdgcn_mfma_f32_16x16x32_bf16(a, b, acc[c], 0, 0, 0);
            }
        }
#pragma unroll
        for (int c = 0; c < 2; ++c) {
            int col = bn + c * 16 + lr;
#pragma unroll
            for (int q = 0; q < 4; ++q)
                hw2b[(size_t)(base + rq + q) * 128 + col] = f2bf(acc[c][q]);
        }
    }
}

// ---------------------------------------------------------------------------
// fused conv2: block = 16 nodes, subgroup-per-node agg over both lists.
// ---------------------------------------------------------------------------
__global__ __launch_bounds__(256, 4) void fused_conv2_kernel(
    const unsigned short* __restrict__ hw2b, unsigned short* __restrict__ h3b,
    const int* __restrict__ wpu, const int* __restrict__ wpi,
    const int* __restrict__ uedges, const int* __restrict__ iedges,
    const float* __restrict__ dinv, const float* __restrict__ b2,
    const unsigned short* __restrict__ Wlt, const float* __restrict__ bl, int nu) {
    __shared__ unsigned short ht[16][136];
    int wid = threadIdx.x >> 6, lane = threadIdx.x & 63;
    int l16 = lane & 15, g = lane >> 4;
    int base = blockIdx.x * 16;
    {
        int loc = wid * 4 + g;
        int v = base + loc;
        float acc[8] = {0.f, 0.f, 0.f, 0.f, 0.f, 0.f, 0.f, 0.f};
        int cu = min(wpu[v], CAPU);
        int ci = min(wpi[v], CAPI);
        gather_sg(hw2b, 0, uedges, v * CAPU, cu, dinv, 0, l16, acc);
        gather_sg(hw2b, nu, iedges, v * CAPI, ci, dinv, nu, l16, acc);
        float dv = dinv[v];
        uint4 sp = *reinterpret_cast<const uint4*>(hw2b + (size_t)v * 128 + l16 * 8);
        float selff[8] = {bflo(sp.x), bfhi(sp.x), bflo(sp.y), bfhi(sp.y),
                          bflo(sp.z), bfhi(sp.z), bflo(sp.w), bfhi(sp.w)};
        union { unsigned short s[8]; uint4 u; } o;
#pragma unroll
        for (int d = 0; d < 8; ++d) {
            float val = (acc[d] + dv * selff[d]) * dv + b2[l16 * 8 + d];
            val = fmaxf(val, 0.f);
            o.s[d] = f2bf(val);
        }
        *reinterpret_cast<uint4*>(&ht[loc][l16 * 8]) = o.u;
    }
    __syncthreads();
    int lr = lane & 15, kg = (lane >> 4) * 8;
    int rq = (lane >> 4) * 4;
    f32x4 acc = {0, 0, 0, 0};
    for (int k0 = 0; k0 < 128; k0 += 32) {
        bf16x8 a = *reinterpret_cast<const bf16x8*>(&ht[lr][k0 + kg]);
        bf16x8 b = *reinterpret_cast<const bf16x8*>(Wlt + (size_t)(wid * 16 + lr) * 128 + k0 + kg);
        acc = __builtin_amdgcn_mfma_f32_16x16x32_bf16(a, b, acc, 0, 0, 0);
    }
    int col = wid * 16 + lr;
    float bs = bl[col];
#pragma unroll
    for (int q = 0; q < 4; ++q) {
        float vv = fmaxf(acc[q] + bs, 0.f);
        h3b[(size_t)(base + rq + q) * 64 + col] = f2bf(vv);
    }
}

// ---------------------------------------------------------------------------
// final GEMM (unchanged)
// ---------------------------------------------------------------------------
__global__ __launch_bounds__(256) void final_gemm_kernel(
    const short* __restrict__ h3b, float* __restrict__ out, int nu, int ni) {
    __shared__ float tile[4][16][65];
    int wid = threadIdx.x >> 6, lane = threadIdx.x & 63;
    int row0 = blockIdx.x * 128 + (wid >> 1) * 64;
    int col0 = blockIdx.y * 128 + (wid & 1) * 64;
    int lr = lane & 15;
    int kg = (lane >> 4) * 8;
    const short* Au = h3b;
    const short* Bi = h3b + (size_t)nu * 64;
    bf16x8 a[4][2], b[4][2];
#pragma unroll
    for (int r = 0; r < 4; ++r)
#pragma unroll
        for (int kt = 0; kt < 2; ++kt) {
            a[r][kt] = *reinterpret_cast<const bf16x8*>(Au + (size_t)(row0 + r * 16 + lr) * 64 + kt * 32 + kg);
            b[r][kt] = *reinterpret_cast<const bf16x8*>(Bi + (size_t)(col0 + r * 16 + lr) * 64 + kt * 32 + kg);
        }
    f32x4 acc[4][4];
#pragma unroll
    for (int r = 0; r < 4; ++r)
#pragma unroll
        for (int c = 0; c < 4; ++c) {
            f32x4 z = {0.f, 0.f, 0.f, 0.f};
            z = __builtin_amdgcn_mfma_f32_16x16x32_bf16(a[r][0], b[c][0], z, 0, 0, 0);
            z = __builtin_amdgcn_mfma_f32_16x16x32_bf16(a[r][1], b[c][1], z, 0, 0, 0);
            acc[r][c] = z;
        }
    int rq = (lane >> 4) * 4;
    int orow = lane >> 4;
#pragma unroll
    for (int r = 0; r < 4; ++r) {
        __syncthreads();
#pragma unroll
        for (int c = 0; c < 4; ++c)
#pragma unroll
            for (int q = 0; q < 4; ++q) {
                float v = acc[r][c][q];
                v = fminf(fmaxf(v, 1.f), 5.f);
                tile[wid][rq + q][c * 16 + lr] = v;
            }
        __syncthreads();
#pragma unroll
        for (int rr = 0; rr < 4; ++rr) {
            float4 vv = *reinterpret_cast<const float4*>(&tile[wid][rr * 4 + orow][lr * 4]);
            *reinterpret_cast<float4*>(
                &out[(size_t)(row0 + r * 16 + rr * 4 + orow) * ni + col0 + lr * 4]) = vv;
        }
    }
}

// ---------------------------------------------------------------------------
extern "C" void kernel_launch(void* const* d_in, const int* in_sizes, int n_in,
                              void* d_out, int out_size, void* d_ws, size_t ws_size,
                              hipStream_t stream) {
    const int*   x   = (const int*)d_in[0];
    const int*   ei  = (const int*)d_in[1];
    const float* emb = (const float*)d_in[3];
    const float* W1  = (const float*)d_in[4];
    const float* b1  = (const float*)d_in[5];
    const float* W2  = (const float*)d_in[6];
    const float* b2  = (const float*)d_in[7];
    const float* Wl  = (const float*)d_in[8];
    const float* bl  = (const float*)d_in[9];
    float* out = (float*)d_out;

    const int n   = in_sizes[0];                 // 16384
    const int E   = in_sizes[1] / 2;             // 524288
    const int h1d = in_sizes[5];                 // 256
    const int d   = in_sizes[4] / h1d;           // 128
    const int embrows = in_sizes[3] / d;         // 8193
    const int nu  = n - (embrows - 1);           // 8192
    const int ni  = n - nu;                      // 8192

    const int* srcp = ei;
    const int* dstp = ei + E;

    char* w = (char*)d_ws;
    int*   wpu     = (int*)(w + 0);
    int*   wpi     = (int*)(w + (64 << 10));
    float* dinv    = (float*)(w + (128 << 10));
    unsigned short* W1t = (unsigned short*)(w + (192 << 10));
    unsigned short* W2t = (unsigned short*)(w + (256 << 10));
    unsigned short* Wlt = (unsigned short*)(w + (320 << 10));
    unsigned short* h0u = (unsigned short*)(w + (340 << 10));
    int*   uedges  = (int*)(w + (1 << 20));
    int*   iedges  = (int*)(w + (5 << 20));
    unsigned short* hib  = (unsigned short*)(w + (9  << 20));
    unsigned short* hw2b = (unsigned short*)(w + (12 << 20));
    unsigned short* h3b  = (unsigned short*)(w + (16 << 20));

    // prep + scatter + dinv
    {
        int total = ni * 16 + 16 + 73728 + 2 * n;
        prep_kernel<<<(total + 255) / 256, 256, 0, stream>>>(
            x, emb, W1, W2, Wl, hib, h0u, W1t, W2t, Wlt, wpu, wpi, nu, n);
    }
    scatter_kernel<<<(E + 255) / 256, 256, 0, stream>>>(srcp, dstp, wpu, wpi,
                                                        uedges, iedges, nu, E);
    dinv_kernel<<<(n + 255) / 256, 256, 0, stream>>>(wpu, wpi, dinv, n);

    // conv1 fused: subgroup-per-node agg -> gemm1 -> gemm2  => hw2
    fused_conv1_kernel<<<n / 16, 256, 0, stream>>>(
        hib, h0u, hw2b, wpu, wpi, uedges, iedges, dinv, W1t, b1, W2t, nu);

    // conv2 fused: subgroup-per-node agg -> gemm3  => h3
    fused_conv2_kernel<<<n / 16, 256, 0, stream>>>(
        hw2b, h3b, wpu, wpi, uedges, iedges, dinv, b2, Wlt, bl, nu);

    // result = clip(users @ items.T, 1, 5)
    {
        dim3 g(nu / 128, ni / 128);
        final_gemm_kernel<<<g, 256, 0, stream>>>((const short*)h3b, out, nu, ni);
    }
}

// Round 20
// 137.261 us; speedup vs baseline: 1.0784x; 1.0784x over previous
//
#include <hip/hip_runtime.h>
#include <hip/hip_bf16.h>

#define CAPU 64
#define CAPI 64

typedef __attribute__((ext_vector_type(8))) short bf16x8;
typedef __attribute__((ext_vector_type(4))) float f32x4;
typedef __attribute__((ext_vector_type(4))) unsigned int u32x4;

static __device__ __forceinline__ float bflo(unsigned int w) {
    union { unsigned int i; float f; } u; u.i = w << 16; return u.f;
}
static __device__ __forceinline__ float bfhi(unsigned int w) {
    union { unsigned int i; float f; } u; u.i = w & 0xffff0000u; return u.f;
}
static __device__ __forceinline__ unsigned short f2bf(float f) {
    __hip_bfloat16 h = __float2bfloat16(f);
    union { __hip_bfloat16 b; unsigned short s; } u; u.b = h; return u.s;
}

// ---------------------------------------------------------------------------
// split scatter (R17 version: all accesses normally cached)
// ---------------------------------------------------------------------------
__global__ void scatter_kernel(const int* __restrict__ src, const int* __restrict__ dst,
                               int* __restrict__ wpu, int* __restrict__ wpi,
                               int* __restrict__ uedges, int* __restrict__ iedges,
                               int nu, int E) {
    int e = blockIdx.x * blockDim.x + threadIdx.x;
    if (e < E) {
        int d = dst[e];
        int s = src[e];
        if (s < nu) {
            int p = atomicAdd(&wpu[d], 1);
            if (p < CAPU) uedges[d * CAPU + p] = s;
        } else {
            int p = atomicAdd(&wpi[d], 1);
            if (p < CAPI) iedges[d * CAPI + p] = s - nu;
        }
    }
}

__global__ void dinv_kernel(const int* __restrict__ wpu, const int* __restrict__ wpi,
                            float* __restrict__ dinv, int n) {
    int v = blockIdx.x * blockDim.x + threadIdx.x;
    if (v < n) dinv[v] = rsqrtf((float)(wpu[v] + wpi[v] + 1));
}

// ---------------------------------------------------------------------------
// merged prep (unchanged)
// ---------------------------------------------------------------------------
__global__ void prep_kernel(const int* __restrict__ x, const float* __restrict__ emb,
                            const float* __restrict__ W1, const float* __restrict__ W2,
                            const float* __restrict__ Wl,
                            unsigned short* __restrict__ hi,
                            unsigned short* __restrict__ h0u,
                            unsigned short* __restrict__ W1t,
                            unsigned short* __restrict__ W2t,
                            unsigned short* __restrict__ Wlt,
                            int* __restrict__ wpu, int* __restrict__ wpi,
                            int nu, int n) {
    int i = blockIdx.x * blockDim.x + threadIdx.x;
    int ni = n - nu;
    int HI = ni * 16;
    if (i < HI) {
        int it = i >> 4, c8 = i & 15;
        int row = x[nu + it] - nu + 1;
        float4 f0 = reinterpret_cast<const float4*>(emb)[(size_t)row * 32 + c8 * 2];
        float4 f1 = reinterpret_cast<const float4*>(emb)[(size_t)row * 32 + c8 * 2 + 1];
        union { unsigned short s[8]; uint4 v; } o;
        o.s[0] = f2bf(f0.x); o.s[1] = f2bf(f0.y); o.s[2] = f2bf(f0.z); o.s[3] = f2bf(f0.w);
        o.s[4] = f2bf(f1.x); o.s[5] = f2bf(f1.y); o.s[6] = f2bf(f1.z); o.s[7] = f2bf(f1.w);
        *reinterpret_cast<uint4*>(hi + (size_t)it * 128 + c8 * 8) = o.v;
        return;
    }
    int j = i - HI;
    if (j < 16) {
        int c8 = j;
        float4 f0 = reinterpret_cast<const float4*>(emb)[c8 * 2];
        float4 f1 = reinterpret_cast<const float4*>(emb)[c8 * 2 + 1];
        union { unsigned short s[8]; uint4 v; } o;
        o.s[0] = f2bf(f0.x); o.s[1] = f2bf(f0.y); o.s[2] = f2bf(f0.z); o.s[3] = f2bf(f0.w);
        o.s[4] = f2bf(f1.x); o.s[5] = f2bf(f1.y); o.s[6] = f2bf(f1.z); o.s[7] = f2bf(f1.w);
        *reinterpret_cast<uint4*>(h0u + c8 * 8) = o.v;
        return;
    }
    j -= 16;
    if (j < 32768) {
        int nn = j >> 7, kk = j & 127;
        W1t[j] = f2bf(W1[kk * 256 + nn]);
        return;
    }
    if (j < 65536) {
        int jj = j - 32768;
        int nn = jj >> 8, kk = jj & 255;
        W2t[jj] = f2bf(W2[kk * 128 + nn]);
        return;
    }
    if (j < 73728) {
        int jj = j - 65536;
        int nn = jj >> 7, kk = jj & 127;
        Wlt[jj] = f2bf(Wl[kk * 64 + nn]);
        return;
    }
    int z = j - 73728;
    if (z < n) { wpu[z] = 0; return; }
    z -= n;
    if (z < n) { wpi[z] = 0; }
}

// ---------------------------------------------------------------------------
// acc += w * unpack(row)
// ---------------------------------------------------------------------------
static __device__ __forceinline__ void row_fma(float w, uint4 r, float acc[8]) {
    acc[0] = fmaf(w, bflo(r.x), acc[0]); acc[1] = fmaf(w, bfhi(r.x), acc[1]);
    acc[2] = fmaf(w, bflo(r.y), acc[2]); acc[3] = fmaf(w, bfhi(r.y), acc[3]);
    acc[4] = fmaf(w, bflo(r.z), acc[4]); acc[5] = fmaf(w, bfhi(r.z), acc[5]);
    acc[6] = fmaf(w, bflo(r.w), acc[6]); acc[7] = fmaf(w, bfhi(r.w), acc[7]);
}

// ---------------------------------------------------------------------------
// subgroup-per-node gather (normal cached loads)
// ---------------------------------------------------------------------------
static __device__ __forceinline__ void gather_sg(
    const unsigned short* __restrict__ in, int rofs,
    const int* __restrict__ lst, int base, int cnt,
    const float* __restrict__ dinv, int dofs, int l16, float acc[8]) {
    int e = base, end = base + cnt;
    for (; e + 3 < end; e += 4) {
        int sa = lst[e], sb = lst[e + 1], sc = lst[e + 2], sd = lst[e + 3];
        float wa = dinv[sa + dofs], wb = dinv[sb + dofs];
        float wc = dinv[sc + dofs], wd = dinv[sd + dofs];
        uint4 ra = *reinterpret_cast<const uint4*>(in + (size_t)(sa + rofs) * 128 + l16 * 8);
        uint4 rb = *reinterpret_cast<const uint4*>(in + (size_t)(sb + rofs) * 128 + l16 * 8);
        uint4 rc = *reinterpret_cast<const uint4*>(in + (size_t)(sc + rofs) * 128 + l16 * 8);
        uint4 rd = *reinterpret_cast<const uint4*>(in + (size_t)(sd + rofs) * 128 + l16 * 8);
        row_fma(wa, ra, acc); row_fma(wb, rb, acc);
        row_fma(wc, rc, acc); row_fma(wd, rd, acc);
    }
    for (; e < end; ++e) {
        int sa = lst[e];
        float wa = dinv[sa + dofs];
        uint4 ra = *reinterpret_cast<const uint4*>(in + (size_t)(sa + rofs) * 128 + l16 * 8);
        row_fma(wa, ra, acc);
    }
}

// ---------------------------------------------------------------------------
// fused conv1: subgroup-per-node agg -> gemm1 -> gemm2.
// gemm2 output staged in LDS (zt reuse) then written as 256B-contiguous
// NON-TEMPORAL stores (native vector type): full lines, no L2 allocation
// -> gather table (hi, 2MB) is not evicted by the 4MB write stream.
// ---------------------------------------------------------------------------
__global__ __launch_bounds__(256, 4) void fused_conv1_kernel(
    const unsigned short* __restrict__ hi, const unsigned short* __restrict__ h0u,
    unsigned short* __restrict__ hw2b,
    const int* __restrict__ wpu, const int* __restrict__ wpi,
    const int* __restrict__ uedges, const int* __restrict__ iedges,
    const float* __restrict__ dinv,
    const unsigned short* __restrict__ W1t, const float* __restrict__ b1,
    const unsigned short* __restrict__ W2t, int nu) {
    __shared__ unsigned short zt[16][136];
    __shared__ unsigned short h1t[16][264];
    int wid = threadIdx.x >> 6, lane = threadIdx.x & 63;
    int l16 = lane & 15, g = lane >> 4;
    int base = blockIdx.x * 16;
    {
        int loc = wid * 4 + g;
        int v = base + loc;
        float su = 0.f;
        int cu = min(wpu[v], CAPU);
        for (int u = l16; u < cu; u += 16) su += dinv[uedges[v * CAPU + u]];
        su += __shfl_xor(su, 1, 64);
        su += __shfl_xor(su, 2, 64);
        su += __shfl_xor(su, 4, 64);
        su += __shfl_xor(su, 8, 64);
        float acc[8] = {0.f, 0.f, 0.f, 0.f, 0.f, 0.f, 0.f, 0.f};
        int ci = min(wpi[v], CAPI);
        gather_sg(hi, 0, iedges, v * CAPI, ci, dinv, nu, l16, acc);
        float dv = dinv[v];
        const unsigned short* selfp = (v < nu) ? h0u : (hi + (size_t)(v - nu) * 128);
        uint4 sp = *reinterpret_cast<const uint4*>(selfp + l16 * 8);
        uint4 hu = *reinterpret_cast<const uint4*>(h0u + l16 * 8);
        float selff[8] = {bflo(sp.x), bfhi(sp.x), bflo(sp.y), bfhi(sp.y),
                          bflo(sp.z), bfhi(sp.z), bflo(sp.w), bfhi(sp.w)};
        float huf[8] = {bflo(hu.x), bfhi(hu.x), bflo(hu.y), bfhi(hu.y),
                        bflo(hu.z), bfhi(hu.z), bflo(hu.w), bfhi(hu.w)};
        union { unsigned short s[8]; uint4 u; } o;
#pragma unroll
        for (int d = 0; d < 8; ++d) {
            float val = (acc[d] + su * huf[d] + dv * selff[d]) * dv;
            o.s[d] = f2bf(val);
        }
        *reinterpret_cast<uint4*>(&zt[loc][l16 * 8]) = o.u;
    }
    __syncthreads();
    int lr = lane & 15, kg = (lane >> 4) * 8;
    int rq = (lane >> 4) * 4;
    {   // gemm1: h1 = relu(zt @ W1t^T + b1), wave cols [wid*64,+64), K=128
        int bn = wid * 64;
        f32x4 acc[4] = {{0,0,0,0},{0,0,0,0},{0,0,0,0},{0,0,0,0}};
        for (int k0 = 0; k0 < 128; k0 += 32) {
            bf16x8 a = *reinterpret_cast<const bf16x8*>(&zt[lr][k0 + kg]);
#pragma unroll
            for (int c = 0; c < 4; ++c) {
                bf16x8 b = *reinterpret_cast<const bf16x8*>(W1t + (size_t)(bn + c * 16 + lr) * 128 + k0 + kg);
                acc[c] = __builtin_amdgcn_mfma_f32_16x16x32_bf16(a, b, acc[c], 0, 0, 0);
            }
        }
        __syncthreads();   // all zt reads done before gemm2 stage overwrites it
#pragma unroll
        for (int c = 0; c < 4; ++c) {
            int col = bn + c * 16 + lr;
            float bs = b1[col];
#pragma unroll
            for (int q = 0; q < 4; ++q) {
                float vv = fmaxf(acc[c][q] + bs, 0.f);
                h1t[rq + q][col] = f2bf(vv);
            }
        }
    }
    __syncthreads();
    {   // gemm2: hw2 = h1 @ W2t^T, wave cols [wid*32,+32), K=256
        int bn = wid * 32;
        f32x4 acc[2] = {{0,0,0,0},{0,0,0,0}};
        for (int k0 = 0; k0 < 256; k0 += 32) {
            bf16x8 a = *reinterpret_cast<const bf16x8*>(&h1t[lr][k0 + kg]);
#pragma unroll
            for (int c = 0; c < 2; ++c) {
                bf16x8 b = *reinterpret_cast<const bf16x8*>(W2t + (size_t)(bn + c * 16 + lr) * 256 + k0 + kg);
                acc[c] = __builtin_amdgcn_mfma_f32_16x16x32_bf16(a, b, acc[c], 0, 0, 0);
            }
        }
        // stage fragment into zt (dead), then stream out as full-line nt stores
#pragma unroll
        for (int c = 0; c < 2; ++c) {
            int col = bn + c * 16 + lr;
#pragma unroll
            for (int q = 0; q < 4; ++q)
                zt[rq + q][col] = f2bf(acc[c][q]);
        }
        __syncthreads();
        int loc = wid * 4 + g;
        u32x4 vv = *reinterpret_cast<const u32x4*>(&zt[loc][l16 * 8]);
        __builtin_nontemporal_store(
            vv, reinterpret_cast<u32x4*>(hw2b + (size_t)(base + loc) * 128 + l16 * 8));
    }
}

// ---------------------------------------------------------------------------
// fused conv2 (R17 version, unchanged)
// ---------------------------------------------------------------------------
__global__ __launch_bounds__(256, 4) void fused_conv2_kernel(
    const unsigned short* __restrict__ hw2b, unsigned short* __restrict__ h3b,
    const int* __restrict__ wpu, const int* __restrict__ wpi,
    const int* __restrict__ uedges, const int* __restrict__ iedges,
    const float* __restrict__ dinv, const float* __restrict__ b2,
    const unsigned short* __restrict__ Wlt, const float* __restrict__ bl, int nu) {
    __shared__ unsigned short ht[16][136];
    int wid = threadIdx.x >> 6, lane = threadIdx.x & 63;
    int l16 = lane & 15, g = lane >> 4;
    int base = blockIdx.x * 16;
    {
        int loc = wid * 4 + g;
        int v = base + loc;
        float acc[8] = {0.f, 0.f, 0.f, 0.f, 0.f, 0.f, 0.f, 0.f};
        int cu = min(wpu[v], CAPU);
        int ci = min(wpi[v], CAPI);
        gather_sg(hw2b, 0, uedges, v * CAPU, cu, dinv, 0, l16, acc);
        gather_sg(hw2b, nu, iedges, v * CAPI, ci, dinv, nu, l16, acc);
        float dv = dinv[v];
        uint4 sp = *reinterpret_cast<const uint4*>(hw2b + (size_t)v * 128 + l16 * 8);
        float selff[8] = {bflo(sp.x), bfhi(sp.x), bflo(sp.y), bfhi(sp.y),
                          bflo(sp.z), bfhi(sp.z), bflo(sp.w), bfhi(sp.w)};
        union { unsigned short s[8]; uint4 u; } o;
#pragma unroll
        for (int d = 0; d < 8; ++d) {
            float val = (acc[d] + dv * selff[d]) * dv + b2[l16 * 8 + d];
            val = fmaxf(val, 0.f);
            o.s[d] = f2bf(val);
        }
        *reinterpret_cast<uint4*>(&ht[loc][l16 * 8]) = o.u;
    }
    __syncthreads();
    int lr = lane & 15, kg = (lane >> 4) * 8;
    int rq = (lane >> 4) * 4;
    f32x4 acc = {0, 0, 0, 0};
    for (int k0 = 0; k0 < 128; k0 += 32) {
        bf16x8 a = *reinterpret_cast<const bf16x8*>(&ht[lr][k0 + kg]);
        bf16x8 b = *reinterpret_cast<const bf16x8*>(Wlt + (size_t)(wid * 16 + lr) * 128 + k0 + kg);
        acc = __builtin_amdgcn_mfma_f32_16x16x32_bf16(a, b, acc, 0, 0, 0);
    }
    int col = wid * 16 + lr;
    float bs = bl[col];
#pragma unroll
    for (int q = 0; q < 4; ++q) {
        float vv = fmaxf(acc[q] + bs, 0.f);
        h3b[(size_t)(base + rq + q) * 64 + col] = f2bf(vv);
    }
}

// ---------------------------------------------------------------------------
// final GEMM (unchanged)
// ---------------------------------------------------------------------------
__global__ __launch_bounds__(256) void final_gemm_kernel(
    const short* __restrict__ h3b, float* __restrict__ out, int nu, int ni) {
    __shared__ float tile[4][16][65];
    int wid = threadIdx.x >> 6, lane = threadIdx.x & 63;
    int row0 = blockIdx.x * 128 + (wid >> 1) * 64;
    int col0 = blockIdx.y * 128 + (wid & 1) * 64;
    int lr = lane & 15;
    int kg = (lane >> 4) * 8;
    const short* Au = h3b;
    const short* Bi = h3b + (size_t)nu * 64;
    bf16x8 a[4][2], b[4][2];
#pragma unroll
    for (int r = 0; r < 4; ++r)
#pragma unroll
        for (int kt = 0; kt < 2; ++kt) {
            a[r][kt] = *reinterpret_cast<const bf16x8*>(Au + (size_t)(row0 + r * 16 + lr) * 64 + kt * 32 + kg);
            b[r][kt] = *reinterpret_cast<const bf16x8*>(Bi + (size_t)(col0 + r * 16 + lr) * 64 + kt * 32 + kg);
        }
    f32x4 acc[4][4];
#pragma unroll
    for (int r = 0; r < 4; ++r)
#pragma unroll
        for (int c = 0; c < 4; ++c) {
            f32x4 z = {0.f, 0.f, 0.f, 0.f};
            z = __builtin_amdgcn_mfma_f32_16x16x32_bf16(a[r][0], b[c][0], z, 0, 0, 0);
            z = __builtin_amdgcn_mfma_f32_16x16x32_bf16(a[r][1], b[c][1], z, 0, 0, 0);
            acc[r][c] = z;
        }
    int rq = (lane >> 4) * 4;
    int orow = lane >> 4;
#pragma unroll
    for (int r = 0; r < 4; ++r) {
        __syncthreads();
#pragma unroll
        for (int c = 0; c < 4; ++c)
#pragma unroll
            for (int q = 0; q < 4; ++q) {
                float v = acc[r][c][q];
                v = fminf(fmaxf(v, 1.f), 5.f);
                tile[wid][rq + q][c * 16 + lr] = v;
            }
        __syncthreads();
#pragma unroll
        for (int rr = 0; rr < 4; ++rr) {
            float4 vv = *reinterpret_cast<const float4*>(&tile[wid][rr * 4 + orow][lr * 4]);
            *reinterpret_cast<float4*>(
                &out[(size_t)(row0 + r * 16 + rr * 4 + orow) * ni + col0 + lr * 4]) = vv;
        }
    }
}

// ---------------------------------------------------------------------------
extern "C" void kernel_launch(void* const* d_in, const int* in_sizes, int n_in,
                              void* d_out, int out_size, void* d_ws, size_t ws_size,
                              hipStream_t stream) {
    const int*   x   = (const int*)d_in[0];
    const int*   ei  = (const int*)d_in[1];
    const float* emb = (const float*)d_in[3];
    const float* W1  = (const float*)d_in[4];
    const float* b1  = (const float*)d_in[5];
    const float* W2  = (const float*)d_in[6];
    const float* b2  = (const float*)d_in[7];
    const float* Wl  = (const float*)d_in[8];
    const float* bl  = (const float*)d_in[9];
    float* out = (float*)d_out;

    const int n   = in_sizes[0];                 // 16384
    const int E   = in_sizes[1] / 2;             // 524288
    const int h1d = in_sizes[5];                 // 256
    const int d   = in_sizes[4] / h1d;           // 128
    const int embrows = in_sizes[3] / d;         // 8193
    const int nu  = n - (embrows - 1);           // 8192
    const int ni  = n - nu;                      // 8192

    const int* srcp = ei;
    const int* dstp = ei + E;

    char* w = (char*)d_ws;
    int*   wpu     = (int*)(w + 0);
    int*   wpi     = (int*)(w + (64 << 10));
    float* dinv    = (float*)(w + (128 << 10));
    unsigned short* W1t = (unsigned short*)(w + (192 << 10));
    unsigned short* W2t = (unsigned short*)(w + (256 << 10));
    unsigned short* Wlt = (unsigned short*)(w + (320 << 10));
    unsigned short* h0u = (unsigned short*)(w + (340 << 10));
    int*   uedges  = (int*)(w + (1 << 20));
    int*   iedges  = (int*)(w + (5 << 20));
    unsigned short* hib  = (unsigned short*)(w + (9  << 20));
    unsigned short* hw2b = (unsigned short*)(w + (12 << 20));
    unsigned short* h3b  = (unsigned short*)(w + (16 << 20));

    // prep + scatter + dinv
    {
        int total = ni * 16 + 16 + 73728 + 2 * n;
        prep_kernel<<<(total + 255) / 256, 256, 0, stream>>>(
            x, emb, W1, W2, Wl, hib, h0u, W1t, W2t, Wlt, wpu, wpi, nu, n);
    }
    scatter_kernel<<<(E + 255) / 256, 256, 0, stream>>>(srcp, dstp, wpu, wpi,
                                                        uedges, iedges, nu, E);
    dinv_kernel<<<(n + 255) / 256, 256, 0, stream>>>(wpu, wpi, dinv, n);

    // conv1 fused: agg -> gemm1 -> gemm2 (nt full-line output)  => hw2
    fused_conv1_kernel<<<n / 16, 256, 0, stream>>>(
        hib, h0u, hw2b, wpu, wpi, uedges, iedges, dinv, W1t, b1, W2t, nu);

    // conv2 fused: agg -> gemm3  => h3
    fused_conv2_kernel<<<n / 16, 256, 0, stream>>>(
        hw2b, h3b, wpu, wpi, uedges, iedges, dinv, b2, Wlt, bl, nu);

    // result = clip(users @ items.T, 1, 5)
    {
        dim3 g(nu / 128, ni / 128);
        final_gemm_kernel<<<g, 256, 0, stream>>>((const short*)h3b, out, nu, ni);
    }
}

// Round 21
// 132.872 us; speedup vs baseline: 1.1141x; 1.0330x over previous
//
#include <hip/hip_runtime.h>
#include <hip/hip_bf16.h>

#define CAPU 64
#define CAPI 64

typedef __attribute__((ext_vector_type(8))) short bf16x8;
typedef __attribute__((ext_vector_type(4))) float f32x4;
typedef __attribute__((ext_vector_type(4))) unsigned int u32x4;

static __device__ __forceinline__ float bflo(unsigned int w) {
    union { unsigned int i; float f; } u; u.i = w << 16; return u.f;
}
static __device__ __forceinline__ float bfhi(unsigned int w) {
    union { unsigned int i; float f; } u; u.i = w & 0xffff0000u; return u.f;
}
static __device__ __forceinline__ unsigned short f2bf(float f) {
    __hip_bfloat16 h = __float2bfloat16(f);
    union { __hip_bfloat16 b; unsigned short s; } u; u.b = h; return u.s;
}

// ---------------------------------------------------------------------------
// split scatter with 16-BIT edge indices (ids < 8192 after split):
// halves edge-stream bytes in convs (L2 pollution) and scatter store traffic.
// ---------------------------------------------------------------------------
__global__ void scatter_kernel(const int* __restrict__ src, const int* __restrict__ dst,
                               int* __restrict__ wpu, int* __restrict__ wpi,
                               unsigned short* __restrict__ uedges,
                               unsigned short* __restrict__ iedges,
                               int nu, int E) {
    int e = blockIdx.x * blockDim.x + threadIdx.x;
    if (e < E) {
        int d = dst[e];
        int s = src[e];
        if (s < nu) {
            int p = atomicAdd(&wpu[d], 1);
            if (p < CAPU) uedges[d * CAPU + p] = (unsigned short)s;
        } else {
            int p = atomicAdd(&wpi[d], 1);
            if (p < CAPI) iedges[d * CAPI + p] = (unsigned short)(s - nu);
        }
    }
}

__global__ void dinv_kernel(const int* __restrict__ wpu, const int* __restrict__ wpi,
                            float* __restrict__ dinv, int n) {
    int v = blockIdx.x * blockDim.x + threadIdx.x;
    if (v < n) dinv[v] = rsqrtf((float)(wpu[v] + wpi[v] + 1));
}

// ---------------------------------------------------------------------------
// merged prep (unchanged)
// ---------------------------------------------------------------------------
__global__ void prep_kernel(const int* __restrict__ x, const float* __restrict__ emb,
                            const float* __restrict__ W1, const float* __restrict__ W2,
                            const float* __restrict__ Wl,
                            unsigned short* __restrict__ hi,
                            unsigned short* __restrict__ h0u,
                            unsigned short* __restrict__ W1t,
                            unsigned short* __restrict__ W2t,
                            unsigned short* __restrict__ Wlt,
                            int* __restrict__ wpu, int* __restrict__ wpi,
                            int nu, int n) {
    int i = blockIdx.x * blockDim.x + threadIdx.x;
    int ni = n - nu;
    int HI = ni * 16;
    if (i < HI) {
        int it = i >> 4, c8 = i & 15;
        int row = x[nu + it] - nu + 1;
        float4 f0 = reinterpret_cast<const float4*>(emb)[(size_t)row * 32 + c8 * 2];
        float4 f1 = reinterpret_cast<const float4*>(emb)[(size_t)row * 32 + c8 * 2 + 1];
        union { unsigned short s[8]; uint4 v; } o;
        o.s[0] = f2bf(f0.x); o.s[1] = f2bf(f0.y); o.s[2] = f2bf(f0.z); o.s[3] = f2bf(f0.w);
        o.s[4] = f2bf(f1.x); o.s[5] = f2bf(f1.y); o.s[6] = f2bf(f1.z); o.s[7] = f2bf(f1.w);
        *reinterpret_cast<uint4*>(hi + (size_t)it * 128 + c8 * 8) = o.v;
        return;
    }
    int j = i - HI;
    if (j < 16) {
        int c8 = j;
        float4 f0 = reinterpret_cast<const float4*>(emb)[c8 * 2];
        float4 f1 = reinterpret_cast<const float4*>(emb)[c8 * 2 + 1];
        union { unsigned short s[8]; uint4 v; } o;
        o.s[0] = f2bf(f0.x); o.s[1] = f2bf(f0.y); o.s[2] = f2bf(f0.z); o.s[3] = f2bf(f0.w);
        o.s[4] = f2bf(f1.x); o.s[5] = f2bf(f1.y); o.s[6] = f2bf(f1.z); o.s[7] = f2bf(f1.w);
        *reinterpret_cast<uint4*>(h0u + c8 * 8) = o.v;
        return;
    }
    j -= 16;
    if (j < 32768) {
        int nn = j >> 7, kk = j & 127;
        W1t[j] = f2bf(W1[kk * 256 + nn]);
        return;
    }
    if (j < 65536) {
        int jj = j - 32768;
        int nn = jj >> 8, kk = jj & 255;
        W2t[jj] = f2bf(W2[kk * 128 + nn]);
        return;
    }
    if (j < 73728) {
        int jj = j - 65536;
        int nn = jj >> 7, kk = jj & 127;
        Wlt[jj] = f2bf(Wl[kk * 64 + nn]);
        return;
    }
    int z = j - 73728;
    if (z < n) { wpu[z] = 0; return; }
    z -= n;
    if (z < n) { wpi[z] = 0; }
}

// ---------------------------------------------------------------------------
// acc += w * unpack(row)
// ---------------------------------------------------------------------------
static __device__ __forceinline__ void row_fma(float w, uint4 r, float acc[8]) {
    acc[0] = fmaf(w, bflo(r.x), acc[0]); acc[1] = fmaf(w, bfhi(r.x), acc[1]);
    acc[2] = fmaf(w, bflo(r.y), acc[2]); acc[3] = fmaf(w, bfhi(r.y), acc[3]);
    acc[4] = fmaf(w, bflo(r.z), acc[4]); acc[5] = fmaf(w, bfhi(r.z), acc[5]);
    acc[6] = fmaf(w, bflo(r.w), acc[6]); acc[7] = fmaf(w, bfhi(r.w), acc[7]);
}

// ---------------------------------------------------------------------------
// subgroup-per-node gather, 16-bit edge indices
// ---------------------------------------------------------------------------
static __device__ __forceinline__ void gather_sg(
    const unsigned short* __restrict__ in, int rofs,
    const unsigned short* __restrict__ lst, int base, int cnt,
    const float* __restrict__ dinv, int dofs, int l16, float acc[8]) {
    int e = base, end = base + cnt;
    for (; e + 3 < end; e += 4) {
        int sa = lst[e], sb = lst[e + 1], sc = lst[e + 2], sd = lst[e + 3];
        float wa = dinv[sa + dofs], wb = dinv[sb + dofs];
        float wc = dinv[sc + dofs], wd = dinv[sd + dofs];
        uint4 ra = *reinterpret_cast<const uint4*>(in + (size_t)(sa + rofs) * 128 + l16 * 8);
        uint4 rb = *reinterpret_cast<const uint4*>(in + (size_t)(sb + rofs) * 128 + l16 * 8);
        uint4 rc = *reinterpret_cast<const uint4*>(in + (size_t)(sc + rofs) * 128 + l16 * 8);
        uint4 rd = *reinterpret_cast<const uint4*>(in + (size_t)(sd + rofs) * 128 + l16 * 8);
        row_fma(wa, ra, acc); row_fma(wb, rb, acc);
        row_fma(wc, rc, acc); row_fma(wd, rd, acc);
    }
    for (; e < end; ++e) {
        int sa = lst[e];
        float wa = dinv[sa + dofs];
        uint4 ra = *reinterpret_cast<const uint4*>(in + (size_t)(sa + rofs) * 128 + l16 * 8);
        row_fma(wa, ra, acc);
    }
}

// ---------------------------------------------------------------------------
// fused conv1: subgroup-per-node agg -> gemm1 -> gemm2 (LDS-staged nt output)
// ---------------------------------------------------------------------------
__global__ __launch_bounds__(256, 4) void fused_conv1_kernel(
    const unsigned short* __restrict__ hi, const unsigned short* __restrict__ h0u,
    unsigned short* __restrict__ hw2b,
    const int* __restrict__ wpu, const int* __restrict__ wpi,
    const unsigned short* __restrict__ uedges, const unsigned short* __restrict__ iedges,
    const float* __restrict__ dinv,
    const unsigned short* __restrict__ W1t, const float* __restrict__ b1,
    const unsigned short* __restrict__ W2t, int nu) {
    __shared__ unsigned short zt[16][136];
    __shared__ unsigned short h1t[16][264];
    int wid = threadIdx.x >> 6, lane = threadIdx.x & 63;
    int l16 = lane & 15, g = lane >> 4;
    int base = blockIdx.x * 16;
    {
        int loc = wid * 4 + g;
        int v = base + loc;
        float su = 0.f;
        int cu = min(wpu[v], CAPU);
        for (int u = l16; u < cu; u += 16) su += dinv[uedges[v * CAPU + u]];
        su += __shfl_xor(su, 1, 64);
        su += __shfl_xor(su, 2, 64);
        su += __shfl_xor(su, 4, 64);
        su += __shfl_xor(su, 8, 64);
        float acc[8] = {0.f, 0.f, 0.f, 0.f, 0.f, 0.f, 0.f, 0.f};
        int ci = min(wpi[v], CAPI);
        gather_sg(hi, 0, iedges, v * CAPI, ci, dinv, nu, l16, acc);
        float dv = dinv[v];
        const unsigned short* selfp = (v < nu) ? h0u : (hi + (size_t)(v - nu) * 128);
        uint4 sp = *reinterpret_cast<const uint4*>(selfp + l16 * 8);
        uint4 hu = *reinterpret_cast<const uint4*>(h0u + l16 * 8);
        float selff[8] = {bflo(sp.x), bfhi(sp.x), bflo(sp.y), bfhi(sp.y),
                          bflo(sp.z), bfhi(sp.z), bflo(sp.w), bfhi(sp.w)};
        float huf[8] = {bflo(hu.x), bfhi(hu.x), bflo(hu.y), bfhi(hu.y),
                        bflo(hu.z), bfhi(hu.z), bflo(hu.w), bfhi(hu.w)};
        union { unsigned short s[8]; uint4 u; } o;
#pragma unroll
        for (int d = 0; d < 8; ++d) {
            float val = (acc[d] + su * huf[d] + dv * selff[d]) * dv;
            o.s[d] = f2bf(val);
        }
        *reinterpret_cast<uint4*>(&zt[loc][l16 * 8]) = o.u;
    }
    __syncthreads();
    int lr = lane & 15, kg = (lane >> 4) * 8;
    int rq = (lane >> 4) * 4;
    {   // gemm1
        int bn = wid * 64;
        f32x4 acc[4] = {{0,0,0,0},{0,0,0,0},{0,0,0,0},{0,0,0,0}};
        for (int k0 = 0; k0 < 128; k0 += 32) {
            bf16x8 a = *reinterpret_cast<const bf16x8*>(&zt[lr][k0 + kg]);
#pragma unroll
            for (int c = 0; c < 4; ++c) {
                bf16x8 b = *reinterpret_cast<const bf16x8*>(W1t + (size_t)(bn + c * 16 + lr) * 128 + k0 + kg);
                acc[c] = __builtin_amdgcn_mfma_f32_16x16x32_bf16(a, b, acc[c], 0, 0, 0);
            }
        }
        __syncthreads();
#pragma unroll
        for (int c = 0; c < 4; ++c) {
            int col = bn + c * 16 + lr;
            float bs = b1[col];
#pragma unroll
            for (int q = 0; q < 4; ++q) {
                float vv = fmaxf(acc[c][q] + bs, 0.f);
                h1t[rq + q][col] = f2bf(vv);
            }
        }
    }
    __syncthreads();
    {   // gemm2 -> LDS stage -> full-line nt stores
        int bn = wid * 32;
        f32x4 acc[2] = {{0,0,0,0},{0,0,0,0}};
        for (int k0 = 0; k0 < 256; k0 += 32) {
            bf16x8 a = *reinterpret_cast<const bf16x8*>(&h1t[lr][k0 + kg]);
#pragma unroll
            for (int c = 0; c < 2; ++c) {
                bf16x8 b = *reinterpret_cast<const bf16x8*>(W2t + (size_t)(bn + c * 16 + lr) * 256 + k0 + kg);
                acc[c] = __builtin_amdgcn_mfma_f32_16x16x32_bf16(a, b, acc[c], 0, 0, 0);
            }
        }
#pragma unroll
        for (int c = 0; c < 2; ++c) {
            int col = bn + c * 16 + lr;
#pragma unroll
            for (int q = 0; q < 4; ++q)
                zt[rq + q][col] = f2bf(acc[c][q]);
        }
        __syncthreads();
        int loc = wid * 4 + g;
        u32x4 vv = *reinterpret_cast<const u32x4*>(&zt[loc][l16 * 8]);
        __builtin_nontemporal_store(
            vv, reinterpret_cast<u32x4*>(hw2b + (size_t)(base + loc) * 128 + l16 * 8));
    }
}

// ---------------------------------------------------------------------------
// fused conv2: subgroup-per-node agg over both (16-bit) lists -> gemm3
// ---------------------------------------------------------------------------
__global__ __launch_bounds__(256, 4) void fused_conv2_kernel(
    const unsigned short* __restrict__ hw2b, unsigned short* __restrict__ h3b,
    const int* __restrict__ wpu, const int* __restrict__ wpi,
    const unsigned short* __restrict__ uedges, const unsigned short* __restrict__ iedges,
    const float* __restrict__ dinv, const float* __restrict__ b2,
    const unsigned short* __restrict__ Wlt, const float* __restrict__ bl, int nu) {
    __shared__ unsigned short ht[16][136];
    int wid = threadIdx.x >> 6, lane = threadIdx.x & 63;
    int l16 = lane & 15, g = lane >> 4;
    int base = blockIdx.x * 16;
    {
        int loc = wid * 4 + g;
        int v = base + loc;
        float acc[8] = {0.f, 0.f, 0.f, 0.f, 0.f, 0.f, 0.f, 0.f};
        int cu = min(wpu[v], CAPU);
        int ci = min(wpi[v], CAPI);
        gather_sg(hw2b, 0, uedges, v * CAPU, cu, dinv, 0, l16, acc);
        gather_sg(hw2b, nu, iedges, v * CAPI, ci, dinv, nu, l16, acc);
        float dv = dinv[v];
        uint4 sp = *reinterpret_cast<const uint4*>(hw2b + (size_t)v * 128 + l16 * 8);
        float selff[8] = {bflo(sp.x), bfhi(sp.x), bflo(sp.y), bfhi(sp.y),
                          bflo(sp.z), bfhi(sp.z), bflo(sp.w), bfhi(sp.w)};
        union { unsigned short s[8]; uint4 u; } o;
#pragma unroll
        for (int d = 0; d < 8; ++d) {
            float val = (acc[d] + dv * selff[d]) * dv + b2[l16 * 8 + d];
            val = fmaxf(val, 0.f);
            o.s[d] = f2bf(val);
        }
        *reinterpret_cast<uint4*>(&ht[loc][l16 * 8]) = o.u;
    }
    __syncthreads();
    int lr = lane & 15, kg = (lane >> 4) * 8;
    int rq = (lane >> 4) * 4;
    f32x4 acc = {0, 0, 0, 0};
    for (int k0 = 0; k0 < 128; k0 += 32) {
        bf16x8 a = *reinterpret_cast<const bf16x8*>(&ht[lr][k0 + kg]);
        bf16x8 b = *reinterpret_cast<const bf16x8*>(Wlt + (size_t)(wid * 16 + lr) * 128 + k0 + kg);
        acc = __builtin_amdgcn_mfma_f32_16x16x32_bf16(a, b, acc, 0, 0, 0);
    }
    int col = wid * 16 + lr;
    float bs = bl[col];
#pragma unroll
    for (int q = 0; q < 4; ++q) {
        float vv = fmaxf(acc[q] + bs, 0.f);
        h3b[(size_t)(base + rq + q) * 64 + col] = f2bf(vv);
    }
}

// ---------------------------------------------------------------------------
// final GEMM (unchanged)
// ---------------------------------------------------------------------------
__global__ __launch_bounds__(256) void final_gemm_kernel(
    const short* __restrict__ h3b, float* __restrict__ out, int nu, int ni) {
    __shared__ float tile[4][16][65];
    int wid = threadIdx.x >> 6, lane = threadIdx.x & 63;
    int row0 = blockIdx.x * 128 + (wid >> 1) * 64;
    int col0 = blockIdx.y * 128 + (wid & 1) * 64;
    int lr = lane & 15;
    int kg = (lane >> 4) * 8;
    const short* Au = h3b;
    const short* Bi = h3b + (size_t)nu * 64;
    bf16x8 a[4][2], b[4][2];
#pragma unroll
    for (int r = 0; r < 4; ++r)
#pragma unroll
        for (int kt = 0; kt < 2; ++kt) {
            a[r][kt] = *reinterpret_cast<const bf16x8*>(Au + (size_t)(row0 + r * 16 + lr) * 64 + kt * 32 + kg);
            b[r][kt] = *reinterpret_cast<const bf16x8*>(Bi + (size_t)(col0 + r * 16 + lr) * 64 + kt * 32 + kg);
        }
    f32x4 acc[4][4];
#pragma unroll
    for (int r = 0; r < 4; ++r)
#pragma unroll
        for (int c = 0; c < 4; ++c) {
            f32x4 z = {0.f, 0.f, 0.f, 0.f};
            z = __builtin_amdgcn_mfma_f32_16x16x32_bf16(a[r][0], b[c][0], z, 0, 0, 0);
            z = __builtin_amdgcn_mfma_f32_16x16x32_bf16(a[r][1], b[c][1], z, 0, 0, 0);
            acc[r][c] = z;
        }
    int rq = (lane >> 4) * 4;
    int orow = lane >> 4;
#pragma unroll
    for (int r = 0; r < 4; ++r) {
        __syncthreads();
#pragma unroll
        for (int c = 0; c < 4; ++c)
#pragma unroll
            for (int q = 0; q < 4; ++q) {
                float v = acc[r][c][q];
                v = fminf(fmaxf(v, 1.f), 5.f);
                tile[wid][rq + q][c * 16 + lr] = v;
            }
        __syncthreads();
#pragma unroll
        for (int rr = 0; rr < 4; ++rr) {
            float4 vv = *reinterpret_cast<const float4*>(&tile[wid][rr * 4 + orow][lr * 4]);
            *reinterpret_cast<float4*>(
                &out[(size_t)(row0 + r * 16 + rr * 4 + orow) * ni + col0 + lr * 4]) = vv;
        }
    }
}

// ---------------------------------------------------------------------------
extern "C" void kernel_launch(void* const* d_in, const int* in_sizes, int n_in,
                              void* d_out, int out_size, void* d_ws, size_t ws_size,
                              hipStream_t stream) {
    const int*   x   = (const int*)d_in[0];
    const int*   ei  = (const int*)d_in[1];
    const float* emb = (const float*)d_in[3];
    const float* W1  = (const float*)d_in[4];
    const float* b1  = (const float*)d_in[5];
    const float* W2  = (const float*)d_in[6];
    const float* b2  = (const float*)d_in[7];
    const float* Wl  = (const float*)d_in[8];
    const float* bl  = (const float*)d_in[9];
    float* out = (float*)d_out;

    const int n   = in_sizes[0];                 // 16384
    const int E   = in_sizes[1] / 2;             // 524288
    const int h1d = in_sizes[5];                 // 256
    const int d   = in_sizes[4] / h1d;           // 128
    const int embrows = in_sizes[3] / d;         // 8193
    const int nu  = n - (embrows - 1);           // 8192
    const int ni  = n - nu;                      // 8192

    const int* srcp = ei;
    const int* dstp = ei + E;

    char* w = (char*)d_ws;
    int*   wpu     = (int*)(w + 0);
    int*   wpi     = (int*)(w + (64 << 10));
    float* dinv    = (float*)(w + (128 << 10));
    unsigned short* W1t = (unsigned short*)(w + (192 << 10));
    unsigned short* W2t = (unsigned short*)(w + (256 << 10));
    unsigned short* Wlt = (unsigned short*)(w + (320 << 10));
    unsigned short* h0u = (unsigned short*)(w + (340 << 10));
    unsigned short* uedges = (unsigned short*)(w + (1 << 20));  // 2 MB
    unsigned short* iedges = (unsigned short*)(w + (3 << 20));  // 2 MB
    unsigned short* hib  = (unsigned short*)(w + (5  << 20));   // 2 MB
    unsigned short* hw2b = (unsigned short*)(w + (8  << 20));   // 4 MB
    unsigned short* h3b  = (unsigned short*)(w + (12 << 20));   // 2 MB

    // prep + scatter + dinv
    {
        int total = ni * 16 + 16 + 73728 + 2 * n;
        prep_kernel<<<(total + 255) / 256, 256, 0, stream>>>(
            x, emb, W1, W2, Wl, hib, h0u, W1t, W2t, Wlt, wpu, wpi, nu, n);
    }
    scatter_kernel<<<(E + 255) / 256, 256, 0, stream>>>(srcp, dstp, wpu, wpi,
                                                        uedges, iedges, nu, E);
    dinv_kernel<<<(n + 255) / 256, 256, 0, stream>>>(wpu, wpi, dinv, n);

    // conv1 fused: agg -> gemm1 -> gemm2 (nt full-line output)  => hw2
    fused_conv1_kernel<<<n / 16, 256, 0, stream>>>(
        hib, h0u, hw2b, wpu, wpi, uedges, iedges, dinv, W1t, b1, W2t, nu);

    // conv2 fused: agg -> gemm3  => h3
    fused_conv2_kernel<<<n / 16, 256, 0, stream>>>(
        hw2b, h3b, wpu, wpi, uedges, iedges, dinv, b2, Wlt, bl, nu);

    // result = clip(users @ items.T, 1, 5)
    {
        dim3 g(nu / 128, ni / 128);
        final_gemm_kernel<<<g, 256, 0, stream>>>((const short*)h3b, out, nu, ni);
    }
}